// Round 1
// baseline (358.676 us; speedup 1.0000x reference)
//
#include <hip/hip_runtime.h>
#include <math.h>

#define B_ 128
#define G_ 16
#define A_ 8732
#define C_ 21
#define THR_ 0.5f
#define NEG_POS_ 3
#define VAR0_ 0.1f
#define VAR1_ 0.2f

struct Accum { float loss_loc; float loss_cls; int n_total; int pad; };

// ---------------------------------------------------------------------------
// K0: zero accumulators
// ---------------------------------------------------------------------------
__global__ void k_init(Accum* acc) {
    acc->loss_loc = 0.f;
    acc->loss_cls = 0.f;
    acc->n_total  = 0;
}

// ---------------------------------------------------------------------------
// K1: per-batch matching. One block (256 thr) per batch.
// Computes IoU(G=16, A=8732), per-anchor max/argmax over g (first-occurrence),
// per-gt max/argmax over a (first-occurrence = min index on ties), applies the
// forced-match scatter, emits packed (conf | gt<<8) per anchor and num_pos.
// ---------------------------------------------------------------------------
__global__ __launch_bounds__(256) void k_match(
    const float* __restrict__ tboxes,   // B,G,4 (point form)
    const int*   __restrict__ tlabels,  // B,G
    const float* __restrict__ anchors,  // A,4 (center form)
    int*         __restrict__ match,    // B*A packed conf|gt<<8
    int*         __restrict__ num_pos,  // B
    Accum*                    acc)
{
    const int b   = blockIdx.x;
    const int tid = threadIdx.x;

    __shared__ float         s_ov[A_];
    __shared__ unsigned char s_gi[A_];
    __shared__ float s_box[G_][4];
    __shared__ float s_area[G_];
    __shared__ int   s_lab[G_];
    __shared__ float s_gval[G_ * 256];
    __shared__ int   s_gidx[G_ * 256];
    __shared__ int   s_red[256];

    if (tid < G_ * 4) ((float*)s_box)[tid] = tboxes[b * G_ * 4 + tid];
    if (tid < G_)     s_lab[tid] = tlabels[b * G_ + tid];
    __syncthreads();
    if (tid < G_) {
        float x0 = s_box[tid][0], y0 = s_box[tid][1];
        float x1 = s_box[tid][2], y1 = s_box[tid][3];
        s_area[tid] = (x1 - x0) * (y1 - y0);
    }
    __syncthreads();

    float bestv[G_]; int besti[G_];
    #pragma unroll
    for (int g = 0; g < G_; ++g) { bestv[g] = -1.0f; besti[g] = 0; }

    for (int a = tid; a < A_; a += 256) {
        float4 an = ((const float4*)anchors)[a];
        float ax0 = an.x - an.z * 0.5f, ay0 = an.y - an.w * 0.5f;
        float ax1 = an.x + an.z * 0.5f, ay1 = an.y + an.w * 0.5f;
        float area_b = (ax1 - ax0) * (ay1 - ay0);   // mirror reference arithmetic
        float bov = -1.f; int bg = 0;
        #pragma unroll
        for (int g = 0; g < G_; ++g) {
            float tlx = fmaxf(s_box[g][0], ax0);
            float tly = fmaxf(s_box[g][1], ay0);
            float brx = fminf(s_box[g][2], ax1);
            float bry = fminf(s_box[g][3], ay1);
            float w = fmaxf(brx - tlx, 0.f);
            float h = fmaxf(bry - tly, 0.f);
            float inter = w * h;
            float iou = inter / (s_area[g] + area_b - inter);
            if (iou > bov) { bov = iou; bg = g; }                       // first g on ties
            if (iou > bestv[g] || (iou == bestv[g] && a < besti[g])) {  // min a on ties
                bestv[g] = iou; besti[g] = a;
            }
        }
        s_ov[a] = bov;
        s_gi[a] = (unsigned char)bg;
    }

    #pragma unroll
    for (int g = 0; g < G_; ++g) {
        s_gval[g * 256 + tid] = bestv[g];
        s_gidx[g * 256 + tid] = besti[g];
    }
    __syncthreads();
    for (int s = 128; s > 0; s >>= 1) {
        if (tid < s) {
            #pragma unroll
            for (int g = 0; g < G_; ++g) {
                float v2 = s_gval[g * 256 + tid + s]; int i2 = s_gidx[g * 256 + tid + s];
                float v1 = s_gval[g * 256 + tid];     int i1 = s_gidx[g * 256 + tid];
                if (v2 > v1 || (v2 == v1 && i2 < i1)) {
                    s_gval[g * 256 + tid] = v2; s_gidx[g * 256 + tid] = i2;
                }
            }
        }
        __syncthreads();
    }
    if (tid == 0) {
        // forced matches: ascending g, last write wins (matches ref loop)
        for (int g = 0; g < G_; ++g) {
            int a = s_gidx[g * 256];
            s_ov[a] = 1.0f;
            s_gi[a] = (unsigned char)g;
        }
    }
    __syncthreads();

    int cnt = 0;
    for (int a = tid; a < A_; a += 256) {
        float ov = s_ov[a];
        int g = s_gi[a];
        int conf = (ov < THR_) ? 0 : (s_lab[g] + 1);
        match[b * A_ + a] = conf | (g << 8);
        cnt += (conf > 0);
    }
    s_red[tid] = cnt; __syncthreads();
    for (int s = 128; s > 0; s >>= 1) {
        if (tid < s) s_red[tid] += s_red[tid + s];
        __syncthreads();
    }
    if (tid == 0) {
        num_pos[b] = s_red[0];
        atomicAdd(&acc->n_total, s_red[0]);
    }
}

// ---------------------------------------------------------------------------
// K2: per-anchor loss. grid = (ceil(A/256), B). Tiles confidences into LDS.
// Computes nll (log-softmax), aux, positive smooth-L1; accumulates
// loss_loc and positive-nll into global accumulators.
// ---------------------------------------------------------------------------
__global__ __launch_bounds__(256) void k_loss(
    const float* __restrict__ pred_off,   // B,A,4
    const float* __restrict__ pred_conf,  // B,A,C
    const float* __restrict__ tboxes,     // B,G,4
    const float* __restrict__ anchors,    // A,4
    const int*   __restrict__ match,
    float*       __restrict__ aux,
    Accum*                    acc)
{
    const int b   = blockIdx.y;
    const int a0  = blockIdx.x * 256;
    const int tid = threadIdx.x;

    __shared__ float s_conf[256 * C_];
    __shared__ float s_red[256];

    const int na = min(256, A_ - a0);
    const float* src = pred_conf + ((size_t)b * A_ + a0) * C_;
    for (int i = tid; i < na * C_; i += 256) s_conf[i] = src[i];
    __syncthreads();

    float lloc = 0.f, pnll = 0.f;
    const int a = a0 + tid;
    if (a < A_) {
        const float* x = &s_conf[tid * C_];
        float m = x[0];
        #pragma unroll
        for (int c = 1; c < C_; ++c) m = fmaxf(m, x[c]);
        float s = 0.f;
        #pragma unroll
        for (int c = 0; c < C_; ++c) s += expf(x[c] - m);
        float lse = m + logf(s);

        int pk   = match[b * A_ + a];
        int conf = pk & 0xff;
        int g    = pk >> 8;
        float nll = lse - x[conf];
        bool pos = conf > 0;
        aux[(size_t)b * A_ + a] = pos ? 0.f : nll;

        if (pos) {
            pnll = nll;
            float4 an = ((const float4*)anchors)[a];
            const float* bx = &tboxes[(b * G_ + g) * 4];
            float gx0 = bx[0], gy0 = bx[1], gx1 = bx[2], gy1 = bx[3];
            float gcx = (gx0 + gx1) * 0.5f, gcy = (gy0 + gy1) * 0.5f;
            float gw = gx1 - gx0, gh = gy1 - gy0;
            float l0 = (gcx - an.x) / (an.z * VAR0_);
            float l1 = (gcy - an.y) / (an.w * VAR0_);
            float l2 = logf(gw / an.z) / VAR1_;
            float l3 = logf(gh / an.w) / VAR1_;
            float4 p = ((const float4*)pred_off)[(size_t)b * A_ + a];
            float d, ad;
            d = p.x - l0; ad = fabsf(d); lloc += (ad < 1.f) ? 0.5f * d * d : ad - 0.5f;
            d = p.y - l1; ad = fabsf(d); lloc += (ad < 1.f) ? 0.5f * d * d : ad - 0.5f;
            d = p.z - l2; ad = fabsf(d); lloc += (ad < 1.f) ? 0.5f * d * d : ad - 0.5f;
            d = p.w - l3; ad = fabsf(d); lloc += (ad < 1.f) ? 0.5f * d * d : ad - 0.5f;
        }
    }

    s_red[tid] = lloc; __syncthreads();
    for (int s = 128; s > 0; s >>= 1) {
        if (tid < s) s_red[tid] += s_red[tid + s];
        __syncthreads();
    }
    if (tid == 0 && s_red[0] != 0.f) atomicAdd(&acc->loss_loc, s_red[0]);
    __syncthreads();
    s_red[tid] = pnll; __syncthreads();
    for (int s = 128; s > 0; s >>= 1) {
        if (tid < s) s_red[tid] += s_red[tid + s];
        __syncthreads();
    }
    if (tid == 0 && s_red[0] != 0.f) atomicAdd(&acc->loss_cls, s_red[0]);
}

// ---------------------------------------------------------------------------
// K3: per-batch hard-negative mining. One block per batch.
// Finds T = K-th largest aux (exact, bitwise binary search — aux >= 0 so the
// uint bit pattern is order-isomorphic), then adds
//   sum_{aux>T} aux + (K - count_gt) * T
// which equals the reference's rank-based selection sum for any tie order.
// ---------------------------------------------------------------------------
__global__ __launch_bounds__(256) void k_select(
    const float* __restrict__ aux,
    const int*   __restrict__ num_pos,
    Accum*                    acc)
{
    const int b   = blockIdx.x;
    const int tid = threadIdx.x;

    __shared__ unsigned int s_bits[A_];
    __shared__ int   s_cnt[256];
    __shared__ float s_sum[256];

    for (int a = tid; a < A_; a += 256)
        s_bits[a] = __float_as_uint(aux[(size_t)b * A_ + a]);
    __syncthreads();

    const int K = min(NEG_POS_ * num_pos[b], A_ - 1);

    unsigned lo = 0u, hi = 0x7f800000u;   // finite non-negative floats < +inf
    while (lo < hi) {
        unsigned mid = (lo + hi) >> 1;
        int c = 0;
        for (int a = tid; a < A_; a += 256) c += (s_bits[a] > mid);
        s_cnt[tid] = c; __syncthreads();
        for (int s = 128; s > 0; s >>= 1) {
            if (tid < s) s_cnt[tid] += s_cnt[tid + s];
            __syncthreads();
        }
        int total = s_cnt[0];
        __syncthreads();
        if (total >= K) lo = mid + 1; else hi = mid;
    }
    // lo == bit pattern of T = K-th largest value

    int c = 0; float sm = 0.f;
    for (int a = tid; a < A_; a += 256) {
        unsigned u = s_bits[a];
        if (u > lo) { c++; sm += __uint_as_float(u); }
    }
    s_cnt[tid] = c; s_sum[tid] = sm; __syncthreads();
    for (int s = 128; s > 0; s >>= 1) {
        if (tid < s) { s_cnt[tid] += s_cnt[tid + s]; s_sum[tid] += s_sum[tid + s]; }
        __syncthreads();
    }
    if (tid == 0) {
        int quota = K - s_cnt[0];
        float T = __uint_as_float(lo);
        atomicAdd(&acc->loss_cls, s_sum[0] + (float)quota * T);
    }
}

// ---------------------------------------------------------------------------
// K4: finalize
// ---------------------------------------------------------------------------
__global__ void k_final(const Accum* __restrict__ acc, float* __restrict__ out) {
    float n = (float)acc->n_total;
    out[0] = acc->loss_loc / n;
    out[1] = acc->loss_cls / n;
}

// ---------------------------------------------------------------------------
extern "C" void kernel_launch(void* const* d_in, const int* in_sizes, int n_in,
                              void* d_out, int out_size, void* d_ws, size_t ws_size,
                              hipStream_t stream) {
    const float* pred_off  = (const float*)d_in[0];  // B,A,4
    const float* pred_conf = (const float*)d_in[1];  // B,A,C
    const float* tboxes    = (const float*)d_in[2];  // B,G,4
    const int*   tlabels   = (const int*)  d_in[3];  // B,G
    const float* anchors   = (const float*)d_in[4];  // A,4
    float* out = (float*)d_out;

    // workspace layout
    char* ws = (char*)d_ws;
    int*   match_ws = (int*)ws;                         ws += (size_t)B_ * A_ * sizeof(int);
    float* aux_ws   = (float*)ws;                       ws += (size_t)B_ * A_ * sizeof(float);
    int*   npos_ws  = (int*)ws;                         ws += (size_t)B_ * sizeof(int);
    Accum* acc      = (Accum*)ws;

    k_init<<<1, 1, 0, stream>>>(acc);
    k_match<<<B_, 256, 0, stream>>>(tboxes, tlabels, anchors, match_ws, npos_ws, acc);
    dim3 g2((A_ + 255) / 256, B_);
    k_loss<<<g2, 256, 0, stream>>>(pred_off, pred_conf, tboxes, anchors, match_ws, aux_ws, acc);
    k_select<<<B_, 256, 0, stream>>>(aux_ws, npos_ws, acc);
    k_final<<<1, 1, 0, stream>>>(acc, out);
}

// Round 2
// 326.729 us; speedup vs baseline: 1.0978x; 1.0978x over previous
//
#include <hip/hip_runtime.h>
#include <math.h>

#define B_ 128
#define G_ 16
#define A_ 8732
#define C_ 21
#define THR_ 0.5f
#define NEG_POS_ 3
#define VAR0_ 0.1f
#define VAR1_ 0.2f

struct Accum { float loss_loc; float loss_cls; int n_total; int pad; };

// ---------------------------------------------------------------------------
// K0: zero accumulators
// ---------------------------------------------------------------------------
__global__ void k_init(Accum* acc) {
    acc->loss_loc = 0.f;
    acc->loss_cls = 0.f;
    acc->n_total  = 0;
}

// ---------------------------------------------------------------------------
// K1: per-batch matching. One 512-thread block per batch (8 waves -> 2/SIMD).
// GT boxes hoisted to registers; per-gt argmax via packed u64 (iou_bits<<32 |
// ~a) wave-shuffle max => exact max-value/min-index semantics.
// ---------------------------------------------------------------------------
__global__ __launch_bounds__(512) void k_match(
    const float* __restrict__ tboxes,   // B,G,4 (point form)
    const int*   __restrict__ tlabels,  // B,G
    const float* __restrict__ anchors,  // A,4 (center form)
    int*         __restrict__ match,    // B*A packed conf|gt<<8
    int*         __restrict__ num_pos,  // B
    Accum*                    acc)
{
    const int b    = blockIdx.x;
    const int tid  = threadIdx.x;
    const int lane = tid & 63;
    const int w    = tid >> 6;          // 0..7

    __shared__ float         s_ov[A_];
    __shared__ unsigned char s_gi[A_];
    __shared__ float s_boxlds[G_ * 4];
    __shared__ int   s_lab[G_];
    __shared__ unsigned long long s_gb[8 * G_];
    __shared__ int   s_forced[G_];
    __shared__ int   s_cnt[8];

    if (tid < G_ * 4) s_boxlds[tid] = tboxes[b * G_ * 4 + tid];
    if (tid < G_)     s_lab[tid]    = tlabels[b * G_ + tid];
    __syncthreads();

    // hoist boxes into registers (broadcast LDS reads, then register-resident)
    float bx0[G_], by0[G_], bx1[G_], by1[G_], bar[G_];
    #pragma unroll
    for (int g = 0; g < G_; ++g) {
        bx0[g] = s_boxlds[g * 4 + 0];
        by0[g] = s_boxlds[g * 4 + 1];
        bx1[g] = s_boxlds[g * 4 + 2];
        by1[g] = s_boxlds[g * 4 + 3];
        bar[g] = (bx1[g] - bx0[g]) * (by1[g] - by0[g]);
    }

    unsigned long long gb[G_];
    #pragma unroll
    for (int g = 0; g < G_; ++g) gb[g] = 0ull;

    for (int a = tid; a < A_; a += 512) {
        float4 an = ((const float4*)anchors)[a];
        float ax0 = an.x - an.z * 0.5f, ay0 = an.y - an.w * 0.5f;
        float ax1 = an.x + an.z * 0.5f, ay1 = an.y + an.w * 0.5f;
        float area_b = (ax1 - ax0) * (ay1 - ay0);   // mirror reference arithmetic
        float bov = -1.f; int bg = 0;
        #pragma unroll
        for (int g = 0; g < G_; ++g) {
            float tlx = fmaxf(bx0[g], ax0);
            float tly = fmaxf(by0[g], ay0);
            float brx = fminf(bx1[g], ax1);
            float bry = fminf(by1[g], ay1);
            float wdt = fmaxf(brx - tlx, 0.f);
            float hgt = fmaxf(bry - tly, 0.f);
            float inter = wdt * hgt;
            float iou = inter / (bar[g] + area_b - inter);
            if (iou > bov) { bov = iou; bg = g; }   // first g wins on ties
            unsigned long long pk =
                ((unsigned long long)__float_as_uint(iou) << 32) |
                (unsigned)(~(unsigned)a);           // max iou, min a on ties
            if (pk > gb[g]) gb[g] = pk;
        }
        s_ov[a] = bov;
        s_gi[a] = (unsigned char)bg;
    }

    // wave reduce the 16 packed maxima
    #pragma unroll
    for (int g = 0; g < G_; ++g) {
        #pragma unroll
        for (int off = 32; off > 0; off >>= 1) {
            unsigned long long o = __shfl_down(gb[g], off);
            if (o > gb[g]) gb[g] = o;
        }
    }
    if (lane == 0) {
        #pragma unroll
        for (int g = 0; g < G_; ++g) s_gb[w * G_ + g] = gb[g];
    }
    __syncthreads();
    if (tid < G_) {
        unsigned long long m = 0ull;
        #pragma unroll
        for (int wv = 0; wv < 8; ++wv) {
            unsigned long long v = s_gb[wv * G_ + tid];
            if (v > m) m = v;
        }
        s_forced[tid] = (int)(~(unsigned)(m & 0xFFFFFFFFull));
    }
    __syncthreads();
    if (tid == 0) {
        // ascending g, last write wins (matches ref loop)
        for (int g = 0; g < G_; ++g) {
            int a = s_forced[g];
            s_ov[a] = 1.0f;
            s_gi[a] = (unsigned char)g;
        }
    }
    __syncthreads();

    int cnt = 0;
    for (int a = tid; a < A_; a += 512) {
        float ov = s_ov[a];
        int g = s_gi[a];
        int conf = (ov < THR_) ? 0 : (s_lab[g] + 1);
        match[b * A_ + a] = conf | (g << 8);
        cnt += (conf > 0);
    }
    #pragma unroll
    for (int off = 32; off > 0; off >>= 1) cnt += __shfl_down(cnt, off);
    if (lane == 0) s_cnt[w] = cnt;
    __syncthreads();
    if (tid == 0) {
        int t = 0;
        #pragma unroll
        for (int wv = 0; wv < 8; ++wv) t += s_cnt[wv];
        num_pos[b] = t;
        atomicAdd(&acc->n_total, t);
    }
}

// ---------------------------------------------------------------------------
// K2: per-anchor loss. grid = (ceil(A/256), B). float4-staged confidences,
// register-resident logits, __expf/__logf, wave-shuffle reductions.
// ---------------------------------------------------------------------------
__global__ __launch_bounds__(256) void k_loss(
    const float* __restrict__ pred_off,   // B,A,4
    const float* __restrict__ pred_conf,  // B,A,C
    const float* __restrict__ tboxes,     // B,G,4
    const float* __restrict__ anchors,    // A,4
    const int*   __restrict__ match,
    float*       __restrict__ aux,
    Accum*                    acc)
{
    const int b    = blockIdx.y;
    const int a0   = blockIdx.x * 256;
    const int tid  = threadIdx.x;
    const int lane = tid & 63;
    const int w    = tid >> 6;

    __shared__ float s_conf[256 * C_];
    __shared__ float s_lloc[4];
    __shared__ float s_pnll[4];

    const int na  = min(256, A_ - a0);        // always a multiple of 4
    const int nv4 = na * C_ / 4;              // exact (na*21 % 4 == 0)
    const float4* src4 = (const float4*)(pred_conf + ((size_t)b * A_ + a0) * C_);
    float4* dst4 = (float4*)s_conf;
    for (int i = tid; i < nv4; i += 256) dst4[i] = src4[i];
    __syncthreads();

    float lloc = 0.f, pnll = 0.f;
    const int a = a0 + tid;
    if (tid < na) {
        float x[C_];
        #pragma unroll
        for (int c = 0; c < C_; ++c) x[c] = s_conf[tid * C_ + c];
        float m = x[0];
        #pragma unroll
        for (int c = 1; c < C_; ++c) m = fmaxf(m, x[c]);
        float s = 0.f;
        #pragma unroll
        for (int c = 0; c < C_; ++c) s += __expf(x[c] - m);
        float lse = m + __logf(s);

        int pk   = match[b * A_ + a];
        int conf = pk & 0xff;
        int g    = pk >> 8;
        float nll = lse - x[conf];
        bool pos = conf > 0;
        aux[(size_t)b * A_ + a] = pos ? 0.f : nll;

        if (pos) {
            pnll = nll;
            float4 an = ((const float4*)anchors)[a];
            const float* bx = &tboxes[(b * G_ + g) * 4];
            float gx0 = bx[0], gy0 = bx[1], gx1 = bx[2], gy1 = bx[3];
            float gcx = (gx0 + gx1) * 0.5f, gcy = (gy0 + gy1) * 0.5f;
            float gw = gx1 - gx0, gh = gy1 - gy0;
            float l0 = (gcx - an.x) / (an.z * VAR0_);
            float l1 = (gcy - an.y) / (an.w * VAR0_);
            float l2 = logf(gw / an.z) / VAR1_;
            float l3 = logf(gh / an.w) / VAR1_;
            float4 p = ((const float4*)pred_off)[(size_t)b * A_ + a];
            float d, ad;
            d = p.x - l0; ad = fabsf(d); lloc += (ad < 1.f) ? 0.5f * d * d : ad - 0.5f;
            d = p.y - l1; ad = fabsf(d); lloc += (ad < 1.f) ? 0.5f * d * d : ad - 0.5f;
            d = p.z - l2; ad = fabsf(d); lloc += (ad < 1.f) ? 0.5f * d * d : ad - 0.5f;
            d = p.w - l3; ad = fabsf(d); lloc += (ad < 1.f) ? 0.5f * d * d : ad - 0.5f;
        }
    }

    #pragma unroll
    for (int off = 32; off > 0; off >>= 1) {
        lloc += __shfl_down(lloc, off);
        pnll += __shfl_down(pnll, off);
    }
    if (lane == 0) { s_lloc[w] = lloc; s_pnll[w] = pnll; }
    __syncthreads();
    if (tid == 0) {
        float L = s_lloc[0] + s_lloc[1] + s_lloc[2] + s_lloc[3];
        float P = s_pnll[0] + s_pnll[1] + s_pnll[2] + s_pnll[3];
        if (L != 0.f) atomicAdd(&acc->loss_loc, L);
        if (P != 0.f) atomicAdd(&acc->loss_cls, P);
    }
}

// ---------------------------------------------------------------------------
// K3: per-batch hard-negative mining. One 1024-thread block per batch.
// Exact K-th-largest via bitwise binary search (aux >= 0), then
//   sum_{aux>T} aux + (K - count_gt) * T  == reference rank-selection sum.
// ---------------------------------------------------------------------------
__global__ __launch_bounds__(1024) void k_select(
    const float* __restrict__ aux,
    const int*   __restrict__ num_pos,
    Accum*                    acc)
{
    const int b    = blockIdx.x;
    const int tid  = threadIdx.x;
    const int lane = tid & 63;
    const int w    = tid >> 6;           // 0..15

    __shared__ unsigned int s_bits[A_];
    __shared__ int   s_c[16];
    __shared__ float s_s[16];

    for (int a = tid; a < A_; a += 1024)
        s_bits[a] = __float_as_uint(aux[(size_t)b * A_ + a]);
    __syncthreads();

    const int K = min(NEG_POS_ * num_pos[b], A_ - 1);

    unsigned lo = 0u, hi = 0x7f800000u;
    while (lo < hi) {
        unsigned mid = (lo + hi) >> 1;
        int c = 0;
        for (int a = tid; a < A_; a += 1024) c += (s_bits[a] > mid);
        #pragma unroll
        for (int off = 32; off > 0; off >>= 1) c += __shfl_down(c, off);
        if (lane == 0) s_c[w] = c;
        __syncthreads();
        int total = 0;
        #pragma unroll
        for (int wv = 0; wv < 16; ++wv) total += s_c[wv];
        __syncthreads();                 // WAR guard before next round's writes
        if (total >= K) lo = mid + 1; else hi = mid;
    }
    // lo == bit pattern of T = K-th largest value

    int c = 0; float sm = 0.f;
    for (int a = tid; a < A_; a += 1024) {
        unsigned u = s_bits[a];
        if (u > lo) { c++; sm += __uint_as_float(u); }
    }
    #pragma unroll
    for (int off = 32; off > 0; off >>= 1) {
        c  += __shfl_down(c, off);
        sm += __shfl_down(sm, off);
    }
    if (lane == 0) { s_c[w] = c; s_s[w] = sm; }
    __syncthreads();
    if (tid == 0) {
        int ct = 0; float st = 0.f;
        #pragma unroll
        for (int wv = 0; wv < 16; ++wv) { ct += s_c[wv]; st += s_s[wv]; }
        float T = __uint_as_float(lo);
        atomicAdd(&acc->loss_cls, st + (float)(K - ct) * T);
    }
}

// ---------------------------------------------------------------------------
// K4: finalize
// ---------------------------------------------------------------------------
__global__ void k_final(const Accum* __restrict__ acc, float* __restrict__ out) {
    float n = (float)acc->n_total;
    out[0] = acc->loss_loc / n;
    out[1] = acc->loss_cls / n;
}

// ---------------------------------------------------------------------------
extern "C" void kernel_launch(void* const* d_in, const int* in_sizes, int n_in,
                              void* d_out, int out_size, void* d_ws, size_t ws_size,
                              hipStream_t stream) {
    const float* pred_off  = (const float*)d_in[0];  // B,A,4
    const float* pred_conf = (const float*)d_in[1];  // B,A,C
    const float* tboxes    = (const float*)d_in[2];  // B,G,4
    const int*   tlabels   = (const int*)  d_in[3];  // B,G
    const float* anchors   = (const float*)d_in[4];  // A,4
    float* out = (float*)d_out;

    // workspace layout
    char* ws = (char*)d_ws;
    int*   match_ws = (int*)ws;                         ws += (size_t)B_ * A_ * sizeof(int);
    float* aux_ws   = (float*)ws;                       ws += (size_t)B_ * A_ * sizeof(float);
    int*   npos_ws  = (int*)ws;                         ws += (size_t)B_ * sizeof(int);
    Accum* acc      = (Accum*)ws;

    k_init<<<1, 1, 0, stream>>>(acc);
    k_match<<<B_, 512, 0, stream>>>(tboxes, tlabels, anchors, match_ws, npos_ws, acc);
    dim3 g2((A_ + 255) / 256, B_);
    k_loss<<<g2, 256, 0, stream>>>(pred_off, pred_conf, tboxes, anchors, match_ws, aux_ws, acc);
    k_select<<<B_, 1024, 0, stream>>>(aux_ws, npos_ws, acc);
    k_final<<<1, 1, 0, stream>>>(acc, out);
}

// Round 3
// 232.462 us; speedup vs baseline: 1.5429x; 1.4055x over previous
//
#include <hip/hip_runtime.h>
#include <math.h>

#define B_ 128
#define G_ 16
#define A_ 8732
#define C_ 21
#define THR_ 0.5f
#define NEG_POS_ 3
#define VAR0_ 0.1f
#define VAR1_ 0.2f

#define BA_   (B_ * A_)          // 1,117,696 (divisible by 4)
#define NTH_  (BA_ / 4)          // 279,424 threads, 4 anchors each
#define NBLK_ ((NTH_ + 255) / 256)   // 1092 blocks

struct Accum { float loss_loc; float loss_cls; int n_total; int pad; };

// ---------------------------------------------------------------------------
// K0: zero accumulators
// ---------------------------------------------------------------------------
__global__ void k_init(Accum* acc) {
    acc->loss_loc = 0.f;
    acc->loss_cls = 0.f;
    acc->n_total  = 0;
}

// ---------------------------------------------------------------------------
// K1: per-batch matching. One 512-thread block per batch.
// ---------------------------------------------------------------------------
__global__ __launch_bounds__(512) void k_match(
    const float* __restrict__ tboxes,   // B,G,4 (point form)
    const int*   __restrict__ tlabels,  // B,G
    const float* __restrict__ anchors,  // A,4 (center form)
    int*         __restrict__ match,    // B*A packed conf|gt<<8
    int*         __restrict__ num_pos,  // B
    Accum*                    acc)
{
    const int b    = blockIdx.x;
    const int tid  = threadIdx.x;
    const int lane = tid & 63;
    const int w    = tid >> 6;          // 0..7

    __shared__ float         s_ov[A_];
    __shared__ unsigned char s_gi[A_];
    __shared__ float s_boxlds[G_ * 4];
    __shared__ int   s_lab[G_];
    __shared__ unsigned long long s_gb[8 * G_];
    __shared__ int   s_forced[G_];
    __shared__ int   s_cnt[8];

    if (tid < G_ * 4) s_boxlds[tid] = tboxes[b * G_ * 4 + tid];
    if (tid < G_)     s_lab[tid]    = tlabels[b * G_ + tid];
    __syncthreads();

    float bx0[G_], by0[G_], bx1[G_], by1[G_], bar[G_];
    #pragma unroll
    for (int g = 0; g < G_; ++g) {
        bx0[g] = s_boxlds[g * 4 + 0];
        by0[g] = s_boxlds[g * 4 + 1];
        bx1[g] = s_boxlds[g * 4 + 2];
        by1[g] = s_boxlds[g * 4 + 3];
        bar[g] = (bx1[g] - bx0[g]) * (by1[g] - by0[g]);
    }

    unsigned long long gb[G_];
    #pragma unroll
    for (int g = 0; g < G_; ++g) gb[g] = 0ull;

    for (int a = tid; a < A_; a += 512) {
        float4 an = ((const float4*)anchors)[a];
        float ax0 = an.x - an.z * 0.5f, ay0 = an.y - an.w * 0.5f;
        float ax1 = an.x + an.z * 0.5f, ay1 = an.y + an.w * 0.5f;
        float area_b = (ax1 - ax0) * (ay1 - ay0);
        float bov = -1.f; int bg = 0;
        #pragma unroll
        for (int g = 0; g < G_; ++g) {
            float tlx = fmaxf(bx0[g], ax0);
            float tly = fmaxf(by0[g], ay0);
            float brx = fminf(bx1[g], ax1);
            float bry = fminf(by1[g], ay1);
            float wdt = fmaxf(brx - tlx, 0.f);
            float hgt = fmaxf(bry - tly, 0.f);
            float inter = wdt * hgt;
            float iou = inter / (bar[g] + area_b - inter);
            if (iou > bov) { bov = iou; bg = g; }   // first g wins on ties
            unsigned long long pk =
                ((unsigned long long)__float_as_uint(iou) << 32) |
                (unsigned)(~(unsigned)a);           // max iou, min a on ties
            if (pk > gb[g]) gb[g] = pk;
        }
        s_ov[a] = bov;
        s_gi[a] = (unsigned char)bg;
    }

    #pragma unroll
    for (int g = 0; g < G_; ++g) {
        #pragma unroll
        for (int off = 32; off > 0; off >>= 1) {
            unsigned long long o = __shfl_down(gb[g], off);
            if (o > gb[g]) gb[g] = o;
        }
    }
    if (lane == 0) {
        #pragma unroll
        for (int g = 0; g < G_; ++g) s_gb[w * G_ + g] = gb[g];
    }
    __syncthreads();
    if (tid < G_) {
        unsigned long long m = 0ull;
        #pragma unroll
        for (int wv = 0; wv < 8; ++wv) {
            unsigned long long v = s_gb[wv * G_ + tid];
            if (v > m) m = v;
        }
        s_forced[tid] = (int)(~(unsigned)(m & 0xFFFFFFFFull));
    }
    __syncthreads();
    if (tid == 0) {
        for (int g = 0; g < G_; ++g) {      // ascending g, last write wins
            int a = s_forced[g];
            s_ov[a] = 1.0f;
            s_gi[a] = (unsigned char)g;
        }
    }
    __syncthreads();

    int cnt = 0;
    for (int a = tid; a < A_; a += 512) {
        float ov = s_ov[a];
        int g = s_gi[a];
        int conf = (ov < THR_) ? 0 : (s_lab[g] + 1);
        match[b * A_ + a] = conf | (g << 8);
        cnt += (conf > 0);
    }
    #pragma unroll
    for (int off = 32; off > 0; off >>= 1) cnt += __shfl_down(cnt, off);
    if (lane == 0) s_cnt[w] = cnt;
    __syncthreads();
    if (tid == 0) {
        int t = 0;
        #pragma unroll
        for (int wv = 0; wv < 8; ++wv) t += s_cnt[wv];
        num_pos[b] = t;
        atomicAdd(&acc->n_total, t);
    }
}

// ---------------------------------------------------------------------------
// K2: per-anchor loss — restructured. NO LDS, NO barriers. Each thread owns
// 4 consecutive anchors = 84 floats = 21 aligned independent float4 loads,
// fully register-resident with static indexing. x[conf] via cndmask chain.
// Per-block partials to ws (no global atomics).
// ---------------------------------------------------------------------------
__global__ __launch_bounds__(256) void k_loss(
    const float* __restrict__ pred_off,   // B,A,4
    const float* __restrict__ pred_conf,  // B,A,C
    const float* __restrict__ tboxes,     // B,G,4
    const float* __restrict__ anchors,    // A,4
    const int*   __restrict__ match,      // flat BA
    float*       __restrict__ aux,        // flat BA
    float*       __restrict__ part_loc,   // NBLK
    float*       __restrict__ part_cls)   // NBLK
{
    const int tid  = threadIdx.x;
    const int t    = blockIdx.x * 256 + tid;
    const int lane = tid & 63;
    const int w    = tid >> 6;

    __shared__ float s_lloc[4];
    __shared__ float s_pnll[4];

    float lloc = 0.f, pnll = 0.f;

    if (t < NTH_) {
        // 21 independent aligned float4 loads -> 84 register floats
        const float4* cp = (const float4*)pred_conf + (size_t)t * 21;
        float xx[84];
        #pragma unroll
        for (int k = 0; k < 21; ++k) {
            float4 v = cp[k];
            xx[4 * k + 0] = v.x; xx[4 * k + 1] = v.y;
            xx[4 * k + 2] = v.z; xx[4 * k + 3] = v.w;
        }
        int4 mk = ((const int4*)match)[t];
        int mkv[4]; mkv[0] = mk.x; mkv[1] = mk.y; mkv[2] = mk.z; mkv[3] = mk.w;
        float auxv[4];

        #pragma unroll
        for (int j = 0; j < 4; ++j) {
            const int base = 21 * j;
            float m = xx[base];
            #pragma unroll
            for (int c = 1; c < C_; ++c) m = fmaxf(m, xx[base + c]);
            float s = 0.f;
            #pragma unroll
            for (int c = 0; c < C_; ++c) s += __expf(xx[base + c] - m);
            float lse = m + __logf(s);

            int conf = mkv[j] & 0xff;
            int g    = mkv[j] >> 8;
            float xc = xx[base];
            #pragma unroll
            for (int c = 1; c < C_; ++c) xc = (conf == c) ? xx[base + c] : xc;
            float nll = lse - xc;
            bool pos = conf > 0;
            auxv[j] = pos ? 0.f : nll;

            if (pos) {
                pnll += nll;
                int i = t * 4 + j;          // flat anchor id
                int b = i / A_;
                int a = i - b * A_;
                float4 an = ((const float4*)anchors)[a];
                float4 bx = ((const float4*)tboxes)[b * G_ + g];
                float gcx = (bx.x + bx.z) * 0.5f, gcy = (bx.y + bx.w) * 0.5f;
                float gw = bx.z - bx.x, gh = bx.w - bx.y;
                float l0 = (gcx - an.x) / (an.z * VAR0_);
                float l1 = (gcy - an.y) / (an.w * VAR0_);
                float l2 = logf(gw / an.z) / VAR1_;
                float l3 = logf(gh / an.w) / VAR1_;
                float4 p = ((const float4*)pred_off)[i];
                float d, ad;
                d = p.x - l0; ad = fabsf(d); lloc += (ad < 1.f) ? 0.5f * d * d : ad - 0.5f;
                d = p.y - l1; ad = fabsf(d); lloc += (ad < 1.f) ? 0.5f * d * d : ad - 0.5f;
                d = p.z - l2; ad = fabsf(d); lloc += (ad < 1.f) ? 0.5f * d * d : ad - 0.5f;
                d = p.w - l3; ad = fabsf(d); lloc += (ad < 1.f) ? 0.5f * d * d : ad - 0.5f;
            }
        }
        ((float4*)aux)[t] = make_float4(auxv[0], auxv[1], auxv[2], auxv[3]);
    }

    #pragma unroll
    for (int off = 32; off > 0; off >>= 1) {
        lloc += __shfl_down(lloc, off);
        pnll += __shfl_down(pnll, off);
    }
    if (lane == 0) { s_lloc[w] = lloc; s_pnll[w] = pnll; }
    __syncthreads();
    if (tid == 0) {
        part_loc[blockIdx.x] = s_lloc[0] + s_lloc[1] + s_lloc[2] + s_lloc[3];
        part_cls[blockIdx.x] = s_pnll[0] + s_pnll[1] + s_pnll[2] + s_pnll[3];
    }
}

// ---------------------------------------------------------------------------
// K3: per-batch hard-negative mining. 256 threads; A values held in 35
// registers/thread; alternating-buffer single-barrier binary-search rounds.
// ---------------------------------------------------------------------------
#define NPT_ 35   // ceil(8732/256)
__global__ __launch_bounds__(256) void k_select(
    const float* __restrict__ aux,
    const int*   __restrict__ num_pos,
    Accum*                    acc)
{
    const int b    = blockIdx.x;
    const int tid  = threadIdx.x;
    const int lane = tid & 63;
    const int w    = tid >> 6;           // 0..3

    __shared__ int   s_c[2][4];
    __shared__ int   s_cf[4];
    __shared__ float s_sf[4];

    unsigned u[NPT_];
    #pragma unroll
    for (int j = 0; j < NPT_; ++j) {
        int a = tid + j * 256;
        u[j] = (a < A_) ? __float_as_uint(aux[(size_t)b * A_ + a]) : 0u;
    }

    const int K = min(NEG_POS_ * num_pos[b], A_ - 1);

    unsigned lo = 0u, hi = 0x7f800000u;
    int it = 0;
    while (lo < hi) {
        unsigned mid = (lo + hi) >> 1;
        int c = 0;
        #pragma unroll
        for (int j = 0; j < NPT_; ++j) c += (u[j] > mid);
        #pragma unroll
        for (int off = 32; off > 0; off >>= 1) c += __shfl_down(c, off);
        if (lane == 0) s_c[it & 1][w] = c;
        __syncthreads();
        int total = s_c[it & 1][0] + s_c[it & 1][1] + s_c[it & 1][2] + s_c[it & 1][3];
        if (total >= K) lo = mid + 1; else hi = mid;
        ++it;
    }
    // lo == bit pattern of T = K-th largest value

    int c = 0; float sm = 0.f;
    #pragma unroll
    for (int j = 0; j < NPT_; ++j) {
        if (u[j] > lo) { c++; sm += __uint_as_float(u[j]); }
    }
    #pragma unroll
    for (int off = 32; off > 0; off >>= 1) {
        c  += __shfl_down(c, off);
        sm += __shfl_down(sm, off);
    }
    if (lane == 0) { s_cf[w] = c; s_sf[w] = sm; }
    __syncthreads();
    if (tid == 0) {
        int   ct = s_cf[0] + s_cf[1] + s_cf[2] + s_cf[3];
        float st = s_sf[0] + s_sf[1] + s_sf[2] + s_sf[3];
        float T = __uint_as_float(lo);
        atomicAdd(&acc->loss_cls, st + (float)(K - ct) * T);
    }
}

// ---------------------------------------------------------------------------
// K4: finalize — reduce per-block partials + accumulators.
// ---------------------------------------------------------------------------
__global__ __launch_bounds__(256) void k_final(
    const Accum* __restrict__ acc,
    const float* __restrict__ part_loc,
    const float* __restrict__ part_cls,
    float*       __restrict__ out)
{
    const int tid  = threadIdx.x;
    const int lane = tid & 63;
    const int w    = tid >> 6;
    __shared__ float s_l[4], s_cl[4];

    float L = 0.f, Cc = 0.f;
    for (int i = tid; i < NBLK_; i += 256) { L += part_loc[i]; Cc += part_cls[i]; }
    #pragma unroll
    for (int off = 32; off > 0; off >>= 1) {
        L  += __shfl_down(L, off);
        Cc += __shfl_down(Cc, off);
    }
    if (lane == 0) { s_l[w] = L; s_cl[w] = Cc; }
    __syncthreads();
    if (tid == 0) {
        float n = (float)acc->n_total;
        float lloc = s_l[0] + s_l[1] + s_l[2] + s_l[3];
        float lcls = s_cl[0] + s_cl[1] + s_cl[2] + s_cl[3] + acc->loss_cls;
        out[0] = lloc / n;
        out[1] = lcls / n;
    }
}

// ---------------------------------------------------------------------------
extern "C" void kernel_launch(void* const* d_in, const int* in_sizes, int n_in,
                              void* d_out, int out_size, void* d_ws, size_t ws_size,
                              hipStream_t stream) {
    const float* pred_off  = (const float*)d_in[0];  // B,A,4
    const float* pred_conf = (const float*)d_in[1];  // B,A,C
    const float* tboxes    = (const float*)d_in[2];  // B,G,4
    const int*   tlabels   = (const int*)  d_in[3];  // B,G
    const float* anchors   = (const float*)d_in[4];  // A,4
    float* out = (float*)d_out;

    // workspace layout (all 16B-aligned)
    char* ws = (char*)d_ws;
    int*   match_ws = (int*)ws;     ws += (size_t)BA_ * sizeof(int);
    float* aux_ws   = (float*)ws;   ws += (size_t)BA_ * sizeof(float);
    float* ploc_ws  = (float*)ws;   ws += (size_t)((NBLK_ + 3) & ~3) * sizeof(float);
    float* pcls_ws  = (float*)ws;   ws += (size_t)((NBLK_ + 3) & ~3) * sizeof(float);
    int*   npos_ws  = (int*)ws;     ws += (size_t)((B_ + 3) & ~3) * sizeof(int);
    Accum* acc      = (Accum*)ws;

    k_init<<<1, 1, 0, stream>>>(acc);
    k_match<<<B_, 512, 0, stream>>>(tboxes, tlabels, anchors, match_ws, npos_ws, acc);
    k_loss<<<NBLK_, 256, 0, stream>>>(pred_off, pred_conf, tboxes, anchors,
                                      match_ws, aux_ws, ploc_ws, pcls_ws);
    k_select<<<B_, 256, 0, stream>>>(aux_ws, npos_ws, acc);
    k_final<<<1, 256, 0, stream>>>(acc, ploc_ws, pcls_ws, out);
}